// Round 6
// baseline (37.740 us; speedup 1.0000x reference)
//
#include <hip/hip_runtime.h>
#include <hip/hip_bf16.h>

typedef __attribute__((ext_vector_type(8))) short bf16x8;
typedef __attribute__((ext_vector_type(4))) float f32x4;
typedef __attribute__((ext_vector_type(16))) float f32x16;
typedef __attribute__((ext_vector_type(2))) unsigned int u32x2;
typedef unsigned short u16;
typedef unsigned int u32;

#define EMB 128
#define HEADS 8
#define HD 16

// round-to-nearest-even fp32 -> bf16
static __device__ __forceinline__ u16 f2bf(float f) {
    union { float f; u32 u; } v; v.f = f;
    u32 u = v.u;
    return (u16)((u + 0x7FFFu + ((u >> 16) & 1u)) >> 16);
}

static __device__ __forceinline__ u32 cvtpk(float a, float b) {
    u32 r;
    asm("v_cvt_pk_bf16_f32 %0, %1, %2" : "=v"(r) : "v"(a), "v"(b));
    return r;
}

// exchange: a' = [a.lo32 | b.lo32(partner)], b' = [a.hi32(partner) | b.hi32]
static __device__ __forceinline__ void plswap(u32& a, u32& b) {
#if __has_builtin(__builtin_amdgcn_permlane32_swap)
    u32x2 r = __builtin_amdgcn_permlane32_swap(a, b, false, false);
    a = r[0]; b = r[1];
#else
    u32 sa = __shfl_xor(a, 32), sb = __shfl_xor(b, 32);
    bool hi = (threadIdx.x & 32) != 0;
    u32 na = hi ? sb : a;
    u32 nb = hi ? b : sa;
    a = na; b = nb;
#endif
}

// ---------------------------------------------------------------------------
// Weight prep: wt[mat][n][k] = bf16(w[mat][k][n]), mat: q,k,v,o
__global__ void __launch_bounds__(256) k_prep(const float* __restrict__ wq,
        const float* __restrict__ wk, const float* __restrict__ wv,
        const float* __restrict__ wo, u16* __restrict__ wt) {
    int i = blockIdx.x * 256 + threadIdx.x;
    int mat = i >> 14, rem = i & 16383;
    int k = rem >> 7, n = rem & 127;
    const float* src = mat == 0 ? wq : mat == 1 ? wk : mat == 2 ? wv : wo;
    wt[mat * 16384 + n * 128 + k] = f2bf(src[rem]);
}

// ---------------------------------------------------------------------------
// Fully fused: LN -> QKV (LDS) -> attention -> out-proj. One block per seq
// row (256 blocks = 256 CUs), 1024 threads = 16 waves.
// Wave w: head h = w&7, token-half hh = w>>3.
// LDS map (132 KB):
//   [0,      34816)  Xs   : LN'd X, [128 tok][136 u16]  (reused as ctxs)
//   [34816,  67584)  Qs   : [8 h][128 tok][16 d] u16, XOR-swz idx^((tok&4)<<1)
//   [67584, 100352)  Ks   : same as Qs
//   [100352,135168)  Vs   : [8 h][16 d][136 tok-pitch] u16
__global__ void __launch_bounds__(1024) k_fused(const float* __restrict__ pe,
        const float* __restrict__ g, const float* __restrict__ bia,
        const u16* __restrict__ wt,
        const float* __restrict__ bq, const float* __restrict__ bk,
        const float* __restrict__ bv, const float* __restrict__ bo,
        const float* __restrict__ mask, float* __restrict__ out) {
    __shared__ __align__(16) char smem[135168];
    u16* Xs = reinterpret_cast<u16*>(smem);            // pitch 136
    u16* Qs = reinterpret_cast<u16*>(smem + 34816);
    u16* Ks = reinterpret_cast<u16*>(smem + 67584);
    u16* Vs = reinterpret_cast<u16*>(smem + 100352);
    char* ctxs = smem;                                  // 256B-pitch, swizzled

    int tid = threadIdx.x;
    int seq = blockIdx.x;
    int lane = tid & 63, w = tid >> 6;
    int h = w & 7, hh = w >> 3;
    int lo = lane & 15, hi = lane >> 4;

    // ---- Phase 1: LayerNorm, 8 threads/token, 128 tokens ----
    {
        int tl = tid >> 3;
        int q = tid & 7;
        const float4* src = reinterpret_cast<const float4*>(pe + (size_t)(seq * 128 + tl) * EMB);
        float4 v[4];
        float s = 0.f, ss = 0.f;
#pragma unroll
        for (int i = 0; i < 4; ++i) {
            v[i] = src[q + i * 8];
            s += v[i].x + v[i].y + v[i].z + v[i].w;
            ss += v[i].x * v[i].x + v[i].y * v[i].y + v[i].z * v[i].z + v[i].w * v[i].w;
        }
        s += __shfl_xor(s, 1); ss += __shfl_xor(ss, 1);
        s += __shfl_xor(s, 2); ss += __shfl_xor(ss, 2);
        s += __shfl_xor(s, 4); ss += __shfl_xor(ss, 4);
        float mean = s * (1.f / EMB);
        float var = ss * (1.f / EMB) - mean * mean;
        float rstd = rsqrtf(var + 1e-5f);
#pragma unroll
        for (int i = 0; i < 4; ++i) {
            int c = (q + i * 8) * 4;
            float4 gg = *reinterpret_cast<const float4*>(g + c);
            float4 bb = *reinterpret_cast<const float4*>(bia + c);
            uint2 packed;
            packed.x = (u32)f2bf((v[i].x - mean) * rstd * gg.x + bb.x)
                     | ((u32)f2bf((v[i].y - mean) * rstd * gg.y + bb.y) << 16);
            packed.y = (u32)f2bf((v[i].z - mean) * rstd * gg.z + bb.z)
                     | ((u32)f2bf((v[i].w - mean) * rstd * gg.w + bb.w) << 16);
            *reinterpret_cast<uint2*>(&Xs[tl * 136 + c]) = packed;
        }
    }
    __syncthreads();

    // ---- Phase 2: per-head QKV GEMM (W in regs). Wave does 4 subtiles. ----
    {
        bf16x8 bf[3][4];
#pragma unroll
        for (int mat = 0; mat < 3; ++mat)
#pragma unroll
            for (int kk = 0; kk < 4; ++kk)
                bf[mat][kk] = *reinterpret_cast<const bf16x8*>(
                    wt + mat * 16384 + (h * 16 + lo) * 128 + kk * 32 + hi * 8);
        // swapped-operand Q/K: d = hi*4+j -> per-thread bias float4
        float4 bq4 = *reinterpret_cast<const float4*>(bq + h * 16 + hi * 4);
        float4 bk4 = *reinterpret_cast<const float4*>(bk + h * 16 + hi * 4);
        float bv_ = bv[h * 16 + lo];

#pragma unroll
        for (int ss = 0; ss < 4; ++ss) {
            int sub = hh * 4 + ss;
            bf16x8 a[4];
#pragma unroll
            for (int kk = 0; kk < 4; ++kk)
                a[kk] = *reinterpret_cast<const bf16x8*>(&Xs[(sub * 16 + lo) * 136 + kk * 32 + hi * 8]);
            f32x4 aq = {}, ak = {}, av = {};
#pragma unroll
            for (int kk = 0; kk < 4; ++kk) {
                // swapped: D col = token = lo, row = d = hi*4+j
                aq = __builtin_amdgcn_mfma_f32_16x16x32_bf16(bf[0][kk], a[kk], aq, 0, 0, 0);
                ak = __builtin_amdgcn_mfma_f32_16x16x32_bf16(bf[1][kk], a[kk], ak, 0, 0, 0);
                // normal: D col = d = lo, row = token = hi*4+j
                av = __builtin_amdgcn_mfma_f32_16x16x32_bf16(a[kk], bf[2][kk], av, 0, 0, 0);
            }
            // Q/K packed write: token = sub*16+lo, d = hi*4..hi*4+3
            {
                int tok = sub * 16 + lo;
                int idx = ((h << 11) + tok * 16 + hi * 4) ^ ((tok & 4) << 1);
                uint2 pq, pk;
                pq.x = (u32)f2bf((aq[0] + bq4.x) * 0.25f) | ((u32)f2bf((aq[1] + bq4.y) * 0.25f) << 16);
                pq.y = (u32)f2bf((aq[2] + bq4.z) * 0.25f) | ((u32)f2bf((aq[3] + bq4.w) * 0.25f) << 16);
                pk.x = (u32)f2bf(ak[0] + bk4.x) | ((u32)f2bf(ak[1] + bk4.y) << 16);
                pk.y = (u32)f2bf(ak[2] + bk4.z) | ((u32)f2bf(ak[3] + bk4.w) << 16);
                *reinterpret_cast<uint2*>(&Qs[idx]) = pq;
                *reinterpret_cast<uint2*>(&Ks[idx]) = pk;
            }
            // V packed write: [d=lo][tok], tok = sub*16 + hi*4 + j
            {
                int tokv = sub * 16 + hi * 4;
                uint2 pv;
                pv.x = (u32)f2bf(av[0] + bv_) | ((u32)f2bf(av[1] + bv_) << 16);
                pv.y = (u32)f2bf(av[2] + bv_) | ((u32)f2bf(av[3] + bv_) << 16);
                *reinterpret_cast<uint2*>(&Vs[h * 2176 + lo * 136 + tokv]) = pv;
            }
        }
    }
    __syncthreads();

    // ---- Phase 3: attention; wave does 2 q-tiles of its head ----
    {
        int lo2 = lane & 31, hi2 = lane >> 5;
        int swz = (lo2 & 4) << 1;            // tok&4 == lo2&4 for tok = t*32+lo2
        const f32x16 zero = {};

        bf16x8 kf[4];
#pragma unroll
        for (int t = 0; t < 4; ++t)
            kf[t] = *reinterpret_cast<const bf16x8*>(
                &Ks[(h << 11) + (((t * 32 + lo2) * 16 + hi2 * 8) ^ swz)]);

#pragma unroll
        for (int qi = 0; qi < 2; ++qi) {
            int qt = hh * 2 + qi;
            bf16x8 qf = *reinterpret_cast<const bf16x8*>(
                &Qs[(h << 11) + (((qt * 32 + lo2) * 16 + hi2 * 8) ^ swz)]);
            f32x16 s[4];
#pragma unroll
            for (int t = 0; t < 4; ++t)
                s[t] = __builtin_amdgcn_mfma_f32_32x32x16_bf16(kf[t], qf, zero, 0, 0, 0);

            float m = s[0][0];
#pragma unroll
            for (int t = 0; t < 4; ++t)
#pragma unroll
                for (int r = 0; r < 16; ++r) m = fmaxf(m, s[t][r]);
            m = fmaxf(m, __shfl_xor(m, 32));
            float sum = 0.f;
#pragma unroll
            for (int t = 0; t < 4; ++t)
#pragma unroll
                for (int r = 0; r < 16; ++r) {
                    float p = __expf(s[t][r] - m);
                    s[t][r] = p;
                    sum += p;
                }
            sum += __shfl_xor(sum, 32);
            float inv = 1.f / sum;

            f32x16 o = {};
#pragma unroll
            for (int c = 0; c < 8; ++c) {
                int t = c >> 1, hf = (c & 1) * 8;
                u32 x0 = cvtpk(s[t][hf + 0], s[t][hf + 1]);
                u32 x1 = cvtpk(s[t][hf + 2], s[t][hf + 3]);
                u32 y0 = cvtpk(s[t][hf + 4], s[t][hf + 5]);
                u32 y1 = cvtpk(s[t][hf + 6], s[t][hf + 7]);
                plswap(x0, y0);
                plswap(x1, y1);
                union { u32 wd[4]; bf16x8 v; } pb;
                pb.wd[0] = x0; pb.wd[1] = x1; pb.wd[2] = y0; pb.wd[3] = y1;
                bf16x8 va = *reinterpret_cast<const bf16x8*>(
                    &Vs[h * 2176 + (lo2 & 15) * 136 + c * 16 + hi2 * 8]);
                o = __builtin_amdgcn_mfma_f32_32x32x16_bf16(va, pb.v, o, 0, 0, 0);
            }

            int tok = qt * 32 + lo2;
            u32 off0 = (u32)(tok * 256 + h * 32 + 8 * hi2) ^ ((tok & 7) << 4);
            u32 off1 = (u32)(tok * 256 + h * 32 + 16 + 8 * hi2) ^ ((tok & 7) << 4);
            uint2 p0, p1;
            p0.x = (u32)f2bf(o[0] * inv) | ((u32)f2bf(o[1] * inv) << 16);
            p0.y = (u32)f2bf(o[2] * inv) | ((u32)f2bf(o[3] * inv) << 16);
            p1.x = (u32)f2bf(o[4] * inv) | ((u32)f2bf(o[5] * inv) << 16);
            p1.y = (u32)f2bf(o[6] * inv) | ((u32)f2bf(o[7] * inv) << 16);
            *reinterpret_cast<uint2*>(ctxs + off0) = p0;
            *reinterpret_cast<uint2*>(ctxs + off1) = p1;
        }
    }
    __syncthreads();

    // ---- Phase 4: out-proj; wave does tokens [(w&7)*16..+16) x cols [hh*64..+64) ----
    {
        const u16* wo = wt + 3 * 16384;
        int tokrow = h * 16 + lo;
        int c0 = hh * 64;
        f32x4 acc[4];
#pragma unroll
        for (int c = 0; c < 4; ++c) acc[c] = f32x4{0.f, 0.f, 0.f, 0.f};
#pragma unroll
        for (int kk = 0; kk < 4; ++kk) {
            u32 aoff = (u32)(tokrow * 256 + kk * 64 + hi * 16) ^ ((tokrow & 7) << 4);
            bf16x8 a = *reinterpret_cast<const bf16x8*>(ctxs + aoff);
#pragma unroll
            for (int c = 0; c < 4; ++c) {
                bf16x8 b = *reinterpret_cast<const bf16x8*>(
                    wo + (c0 + c * 16 + lo) * 128 + kk * 32 + hi * 8);
                acc[c] = __builtin_amdgcn_mfma_f32_16x16x32_bf16(a, b, acc[c], 0, 0, 0);
            }
        }
#pragma unroll
        for (int c = 0; c < 4; ++c) {
            int col = c0 + c * 16 + lo;
            float bval = bo[col];
#pragma unroll
            for (int j = 0; j < 4; ++j) {
                int t = seq * 128 + h * 16 + hi * 4 + j;
                out[(size_t)t * EMB + col] = (acc[c][j] + bval) * mask[t];
            }
        }
    }
}

// ---------------------------------------------------------------------------
extern "C" void kernel_launch(void* const* d_in, const int* in_sizes, int n_in,
                              void* d_out, int out_size, void* d_ws, size_t ws_size,
                              hipStream_t stream) {
    const float* pe   = (const float*)d_in[0];
    const float* mask = (const float*)d_in[1];
    const float* ln_g = (const float*)d_in[2];
    const float* ln_b = (const float*)d_in[3];
    const float* wq   = (const float*)d_in[4];
    const float* bq   = (const float*)d_in[5];
    const float* wk   = (const float*)d_in[6];
    const float* bk   = (const float*)d_in[7];
    const float* wv   = (const float*)d_in[8];
    const float* bv   = (const float*)d_in[9];
    const float* wo   = (const float*)d_in[10];
    const float* bo   = (const float*)d_in[11];
    float* out = (float*)d_out;

    u16* wt = (u16*)d_ws;            // 4 x [n][k] bf16 = 128 KB

    hipLaunchKernelGGL(k_prep,  dim3(256), dim3(256), 0, stream, wq, wk, wv, wo, wt);
    hipLaunchKernelGGL(k_fused, dim3(256), dim3(1024), 0, stream, pe, ln_g, ln_b, wt,
                       bq, bk, bv, bo, mask, out);
}

// Round 9
// 36.814 us; speedup vs baseline: 1.0251x; 1.0251x over previous
//
#include <hip/hip_runtime.h>
#include <hip/hip_bf16.h>

typedef __attribute__((ext_vector_type(8))) short bf16x8;
typedef __attribute__((ext_vector_type(4))) float f32x4;
typedef __attribute__((ext_vector_type(16))) float f32x16;
typedef __attribute__((ext_vector_type(2))) unsigned int u32x2;
typedef unsigned short u16;
typedef unsigned int u32;

#define EMB 128
#define HEADS 8

// round-to-nearest-even fp32 -> bf16
static __device__ __forceinline__ u16 f2bf(float f) {
    union { float f; u32 u; } v; v.f = f;
    u32 u = v.u;
    return (u16)((u + 0x7FFFu + ((u >> 16) & 1u)) >> 16);
}

static __device__ __forceinline__ u32 cvtpk(float a, float b) {
    u32 r;
    asm("v_cvt_pk_bf16_f32 %0, %1, %2" : "=v"(r) : "v"(a), "v"(b));
    return r;
}

// exchange: a' = [a.lo32 | b.lo32(partner)], b' = [a.hi32(partner) | b.hi32]
static __device__ __forceinline__ void plswap(u32& a, u32& b) {
#if __has_builtin(__builtin_amdgcn_permlane32_swap)
    u32x2 r = __builtin_amdgcn_permlane32_swap(a, b, false, false);
    a = r[0]; b = r[1];
#else
    u32 sa = __shfl_xor(a, 32), sb = __shfl_xor(b, 32);
    bool hi = (threadIdx.x & 32) != 0;
    u32 na = hi ? sb : a;
    u32 nb = hi ? b : sa;
    a = na; b = nb;
#endif
}

// ---------------------------------------------------------------------------
// Weight prep: wt[mat][n][k] = bf16(w[mat][k][n]), mat: q,k,v,o
__global__ void __launch_bounds__(256) k_prep(const float* __restrict__ wq,
        const float* __restrict__ wk, const float* __restrict__ wv,
        const float* __restrict__ wo, u16* __restrict__ wt) {
    int i = blockIdx.x * 256 + threadIdx.x;
    int mat = i >> 14, rem = i & 16383;
    int k = rem >> 7, n = rem & 127;
    const float* src = mat == 0 ? wq : mat == 1 ? wk : mat == 2 ? wv : wo;
    wt[mat * 16384 + n * 128 + k] = f2bf(src[rem]);
}

// ---------------------------------------------------------------------------
// Fully fused: LN -> QKV (LDS) -> attention -> out-proj. One block per seq
// row (256 blocks = 256 CUs), 512 threads = 8 waves = 8 heads.
// Round-5 structure (all barriers); round-6's swapped packed Q/K write.
// LDS map (132 KB):
//   [0,      34816)  Xs   : LN'd X, [128 tok][136 u16]  (reused as ctxs)
//   [34816,  67584)  Qs   : [8 h][128 tok][16 d] u16, XOR-swz idx^((tok&4)<<1)
//   [67584, 100352)  Ks   : same as Qs
//   [100352,135168)  Vs   : [8 h][16 d][136 tok-pitch] u16
__global__ void __launch_bounds__(512) k_fused(const float* __restrict__ pe,
        const float* __restrict__ g, const float* __restrict__ bia,
        const u16* __restrict__ wt,
        const float* __restrict__ bq, const float* __restrict__ bk,
        const float* __restrict__ bv, const float* __restrict__ bo,
        const float* __restrict__ mask, float* __restrict__ out) {
    __shared__ __align__(16) char smem[135168];
    u16* Xs = reinterpret_cast<u16*>(smem);            // pitch 136
    u16* Qs = reinterpret_cast<u16*>(smem + 34816);
    u16* Ks = reinterpret_cast<u16*>(smem + 67584);
    u16* Vs = reinterpret_cast<u16*>(smem + 100352);
    char* ctxs = smem;                                  // 256B-pitch, swizzled

    int tid = threadIdx.x;
    int seq = blockIdx.x;
    int lane = tid & 63, h = tid >> 6;
    int lo = lane & 15, hi = lane >> 4;

    // ---- Phase 1: LayerNorm, 4 threads/token, 128 tokens ----
    {
        int tl = tid >> 2;
        int q = tid & 3;
        const float4* src = reinterpret_cast<const float4*>(pe + (size_t)(seq * 128 + tl) * EMB);
        float4 v[8];
        float s = 0.f, ss = 0.f;
#pragma unroll
        for (int i = 0; i < 8; ++i) {
            v[i] = src[i * 4 + q];
            s += v[i].x + v[i].y + v[i].z + v[i].w;
            ss += v[i].x * v[i].x + v[i].y * v[i].y + v[i].z * v[i].z + v[i].w * v[i].w;
        }
        s += __shfl_xor(s, 1); ss += __shfl_xor(ss, 1);
        s += __shfl_xor(s, 2); ss += __shfl_xor(ss, 2);
        float mean = s * (1.f / EMB);
        float var = ss * (1.f / EMB) - mean * mean;
        float rstd = rsqrtf(var + 1e-5f);
#pragma unroll
        for (int i = 0; i < 8; ++i) {
            int c = i * 16 + q * 4;
            float4 gg = *reinterpret_cast<const float4*>(g + c);
            float4 bb = *reinterpret_cast<const float4*>(bia + c);
            uint2 packed;
            packed.x = (u32)f2bf((v[i].x - mean) * rstd * gg.x + bb.x)
                     | ((u32)f2bf((v[i].y - mean) * rstd * gg.y + bb.y) << 16);
            packed.y = (u32)f2bf((v[i].z - mean) * rstd * gg.z + bb.z)
                     | ((u32)f2bf((v[i].w - mean) * rstd * gg.w + bb.w) << 16);
            *reinterpret_cast<uint2*>(&Xs[tl * 136 + c]) = packed;
        }
    }
    __syncthreads();

    // ---- Phase 2: per-head QKV GEMM (W in regs) -> LDS ----
    {
        bf16x8 bf[3][4];
#pragma unroll
        for (int mat = 0; mat < 3; ++mat)
#pragma unroll
            for (int kk = 0; kk < 4; ++kk)
                bf[mat][kk] = *reinterpret_cast<const bf16x8*>(
                    wt + mat * 16384 + (h * 16 + lo) * 128 + kk * 32 + hi * 8);
        // swapped-operand Q/K: d = hi*4+j -> per-thread bias float4
        float4 bq4 = *reinterpret_cast<const float4*>(bq + h * 16 + hi * 4);
        float4 bk4 = *reinterpret_cast<const float4*>(bk + h * 16 + hi * 4);
        float bv_ = bv[h * 16 + lo];

#pragma unroll
        for (int sub = 0; sub < 8; ++sub) {
            bf16x8 a[4];
#pragma unroll
            for (int kk = 0; kk < 4; ++kk)
                a[kk] = *reinterpret_cast<const bf16x8*>(&Xs[(sub * 16 + lo) * 136 + kk * 32 + hi * 8]);
            f32x4 aq = {}, ak = {}, av = {};
#pragma unroll
            for (int kk = 0; kk < 4; ++kk) {
                // swapped: D col = token = lo, row = d = hi*4+j
                aq = __builtin_amdgcn_mfma_f32_16x16x32_bf16(bf[0][kk], a[kk], aq, 0, 0, 0);
                ak = __builtin_amdgcn_mfma_f32_16x16x32_bf16(bf[1][kk], a[kk], ak, 0, 0, 0);
                // normal: D col = d = lo, row = token = hi*4+j
                av = __builtin_amdgcn_mfma_f32_16x16x32_bf16(a[kk], bf[2][kk], av, 0, 0, 0);
            }
            // Q/K packed write: token = sub*16+lo, d = hi*4..hi*4+3
            {
                int tok = sub * 16 + lo;
                int idx = ((h << 11) + tok * 16 + hi * 4) ^ ((tok & 4) << 1);
                uint2 pq, pk;
                pq.x = (u32)f2bf((aq[0] + bq4.x) * 0.25f) | ((u32)f2bf((aq[1] + bq4.y) * 0.25f) << 16);
                pq.y = (u32)f2bf((aq[2] + bq4.z) * 0.25f) | ((u32)f2bf((aq[3] + bq4.w) * 0.25f) << 16);
                pk.x = (u32)f2bf(ak[0] + bk4.x) | ((u32)f2bf(ak[1] + bk4.y) << 16);
                pk.y = (u32)f2bf(ak[2] + bk4.z) | ((u32)f2bf(ak[3] + bk4.w) << 16);
                *reinterpret_cast<uint2*>(&Qs[idx]) = pq;
                *reinterpret_cast<uint2*>(&Ks[idx]) = pk;
            }
            // V packed write: [d=lo][tok], tok = sub*16 + hi*4 + j
            {
                int tokv = sub * 16 + hi * 4;
                uint2 pv;
                pv.x = (u32)f2bf(av[0] + bv_) | ((u32)f2bf(av[1] + bv_) << 16);
                pv.y = (u32)f2bf(av[2] + bv_) | ((u32)f2bf(av[3] + bv_) << 16);
                *reinterpret_cast<uint2*>(&Vs[h * 2176 + lo * 136 + tokv]) = pv;
            }
        }
    }
    __syncthreads();

    // ---- Phase 3: attention (reads Qs/Ks/Vs; writes ctxs = Xs region) ----
    {
        int lo2 = lane & 31, hi2 = lane >> 5;
        int swz = (lo2 & 4) << 1;            // tok&4 == lo2&4 for tok = t*32+lo2
        const f32x16 zero = {};

        bf16x8 kf[4];
#pragma unroll
        for (int t = 0; t < 4; ++t)
            kf[t] = *reinterpret_cast<const bf16x8*>(
                &Ks[(h << 11) + (((t * 32 + lo2) * 16 + hi2 * 8) ^ swz)]);

        for (int qt = 0; qt < 4; ++qt) {
            bf16x8 qf = *reinterpret_cast<const bf16x8*>(
                &Qs[(h << 11) + (((qt * 32 + lo2) * 16 + hi2 * 8) ^ swz)]);
            f32x16 s[4];
#pragma unroll
            for (int t = 0; t < 4; ++t)
                s[t] = __builtin_amdgcn_mfma_f32_32x32x16_bf16(kf[t], qf, zero, 0, 0, 0);

            float m = s[0][0];
#pragma unroll
            for (int t = 0; t < 4; ++t)
#pragma unroll
                for (int r = 0; r < 16; ++r) m = fmaxf(m, s[t][r]);
            m = fmaxf(m, __shfl_xor(m, 32));
            float sum = 0.f;
#pragma unroll
            for (int t = 0; t < 4; ++t)
#pragma unroll
                for (int r = 0; r < 16; ++r) {
                    float p = __expf(s[t][r] - m);
                    s[t][r] = p;
                    sum += p;
                }
            sum += __shfl_xor(sum, 32);
            float inv = 1.f / sum;

            f32x16 o = {};
#pragma unroll
            for (int c = 0; c < 8; ++c) {
                int t = c >> 1, hf = (c & 1) * 8;
                u32 x0 = cvtpk(s[t][hf + 0], s[t][hf + 1]);
                u32 x1 = cvtpk(s[t][hf + 2], s[t][hf + 3]);
                u32 y0 = cvtpk(s[t][hf + 4], s[t][hf + 5]);
                u32 y1 = cvtpk(s[t][hf + 6], s[t][hf + 7]);
                plswap(x0, y0);
                plswap(x1, y1);
                union { u32 wd[4]; bf16x8 v; } pb;
                pb.wd[0] = x0; pb.wd[1] = x1; pb.wd[2] = y0; pb.wd[3] = y1;
                bf16x8 va = *reinterpret_cast<const bf16x8*>(
                    &Vs[h * 2176 + (lo2 & 15) * 136 + c * 16 + hi2 * 8]);
                o = __builtin_amdgcn_mfma_f32_32x32x16_bf16(va, pb.v, o, 0, 0, 0);
            }

            int tok = qt * 32 + lo2;
            u32 off0 = (u32)(tok * 256 + h * 32 + 8 * hi2) ^ ((tok & 7) << 4);
            u32 off1 = (u32)(tok * 256 + h * 32 + 16 + 8 * hi2) ^ ((tok & 7) << 4);
            uint2 p0, p1;
            p0.x = (u32)f2bf(o[0] * inv) | ((u32)f2bf(o[1] * inv) << 16);
            p0.y = (u32)f2bf(o[2] * inv) | ((u32)f2bf(o[3] * inv) << 16);
            p1.x = (u32)f2bf(o[4] * inv) | ((u32)f2bf(o[5] * inv) << 16);
            p1.y = (u32)f2bf(o[6] * inv) | ((u32)f2bf(o[7] * inv) << 16);
            *reinterpret_cast<uint2*>(ctxs + off0) = p0;
            *reinterpret_cast<uint2*>(ctxs + off1) = p1;
        }
    }
    __syncthreads();

    // ---- Phase 4: out-proj; wave h does tokens [h*16, h*16+16) ----
    {
        const u16* wo = wt + 3 * 16384;
        f32x4 acc[8];
#pragma unroll
        for (int c = 0; c < 8; ++c) acc[c] = f32x4{0.f, 0.f, 0.f, 0.f};
#pragma unroll
        for (int kk = 0; kk < 4; ++kk) {
            int tokrow = h * 16 + lo;
            u32 aoff = (u32)(tokrow * 256 + kk * 64 + hi * 16) ^ ((tokrow & 7) << 4);
            bf16x8 a = *reinterpret_cast<const bf16x8*>(ctxs + aoff);
#pragma unroll
            for (int c = 0; c < 8; ++c) {
                bf16x8 b = *reinterpret_cast<const bf16x8*>(wo + (c * 16 + lo) * 128 + kk * 32 + hi * 8);
                acc[c] = __builtin_amdgcn_mfma_f32_16x16x32_bf16(a, b, acc[c], 0, 0, 0);
            }
        }
#pragma unroll
        for (int c = 0; c < 8; ++c) {
            int col = c * 16 + lo;
            float bval = bo[col];
#pragma unroll
            for (int j = 0; j < 4; ++j) {
                int t = seq * 128 + h * 16 + hi * 4 + j;
                out[(size_t)t * EMB + col] = (acc[c][j] + bval) * mask[t];
            }
        }
    }
}

// ---------------------------------------------------------------------------
extern "C" void kernel_launch(void* const* d_in, const int* in_sizes, int n_in,
                              void* d_out, int out_size, void* d_ws, size_t ws_size,
                              hipStream_t stream) {
    const float* pe   = (const float*)d_in[0];
    const float* mask = (const float*)d_in[1];
    const float* ln_g = (const float*)d_in[2];
    const float* ln_b = (const float*)d_in[3];
    const float* wq   = (const float*)d_in[4];
    const float* bq   = (const float*)d_in[5];
    const float* wk   = (const float*)d_in[6];
    const float* bk   = (const float*)d_in[7];
    const float* wv   = (const float*)d_in[8];
    const float* bv   = (const float*)d_in[9];
    const float* wo   = (const float*)d_in[10];
    const float* bo   = (const float*)d_in[11];
    float* out = (float*)d_out;

    u16* wt = (u16*)d_ws;            // 4 x [n][k] bf16 = 128 KB

    hipLaunchKernelGGL(k_prep,  dim3(256), dim3(256), 0, stream, wq, wk, wv, wo, wt);
    hipLaunchKernelGGL(k_fused, dim3(256), dim3(512), 0, stream, pe, ln_g, ln_b, wt,
                       bq, bk, bv, bo, mask, out);
}